// Round 1
// baseline (699.004 us; speedup 1.0000x reference)
//
#include <hip/hip_runtime.h>
#include <stdint.h>

#define COLS 16384
#define POOLCAP 256

typedef unsigned long long u64;

// Order-preserving float32 -> uint32 mapping (ascending float == ascending uint).
__device__ __forceinline__ uint32_t f2key(float x) {
  uint32_t u = __float_as_uint(x);
  u ^= (uint32_t)((int32_t)u >> 31) | 0x80000000u;
  return u;
}

__global__ __launch_bounds__(256) void KNNC_20272245637217_kernel(
    const float* __restrict__ dist,
    const int* __restrict__ labels,
    int* __restrict__ out) {
  const int wave = threadIdx.x >> 6;   // 4 waves per block, one row each
  const int lane = threadIdx.x & 63;
  const int row  = blockIdx.x * 4 + wave;

  __shared__ uint32_t poolU[4][POOLCAP];  // sortable value bits
  __shared__ uint32_t poolI[4][POOLCAP];  // column index
  __shared__ int      cnt[4];

  if (lane == 0) cnt[wave] = 0;
  __syncthreads();

  const float4* rp = (const float4*)(dist + (size_t)row * COLS);

  // ---- Stage A: per-lane min over first 4096 elements (16 float4 steps) ----
  float m = __builtin_inff();
  #pragma unroll
  for (int s = 0; s < 16; ++s) {
    float4 v = rp[s * 64 + lane];
    m = fminf(m, fminf(fminf(v.x, v.y), fminf(v.z, v.w)));
  }

  // ---- Threshold T = 16th smallest of the 64 lane-minima (valid upper bound
  //      on the row's true 16th-smallest; tie-collapse only loosens it, still valid).
  float mv = m, T = m;
  for (int r = 0; r < 16; ++r) {
    float w = mv;
    #pragma unroll
    for (int off = 32; off >= 1; off >>= 1)
      w = fminf(w, __shfl_xor(w, off));
    T = w;
    if (mv == w) mv = __builtin_inff();
  }

  // ---- Stage B: full-row scan, push candidates (v <= T) into LDS pool ----
  #pragma unroll 4
  for (int s = 0; s < 64; ++s) {
    float4 v = rp[s * 64 + lane];
    float mn = fminf(fminf(v.x, v.y), fminf(v.z, v.w));
    if (mn <= T) {
      int colb = s * 256 + lane * 4;
      float xs[4] = {v.x, v.y, v.z, v.w};
      #pragma unroll
      for (int e = 0; e < 4; ++e) {
        if (xs[e] <= T) {
          int slot = atomicAdd(&cnt[wave], 1);
          if (slot < POOLCAP) {
            poolU[wave][slot] = f2key(xs[e]);
            poolI[wave][slot] = colb + e;
          }
        }
      }
    }
  }
  __syncthreads();

  // ---- Exact top-16 extraction from the pool ----
  int C = cnt[wave];
  if (C > POOLCAP) C = POOLCAP;   // defensive; C >= 16 guaranteed by T's construction

  u64 key[4];
  #pragma unroll
  for (int t = 0; t < 4; ++t) {
    int p = lane + 64 * t;
    key[t] = (p < C) ? (((u64)poolU[wave][p] << 32) | (u64)poolI[wave][p]) : ~0ULL;
  }

  u64 myWin = ~0ULL;
  for (int r = 0; r < 16; ++r) {
    u64 k = key[0];
    k = (key[1] < k) ? key[1] : k;
    k = (key[2] < k) ? key[2] : k;
    k = (key[3] < k) ? key[3] : k;
    #pragma unroll
    for (int off = 32; off >= 1; off >>= 1) {
      u64 o = __shfl_xor(k, off);
      k = (o < k) ? o : k;
    }
    if (lane == r) myWin = k;           // lane r records the r-th smallest
    #pragma unroll
    for (int t = 0; t < 4; ++t)
      if (key[t] == k) key[t] = ~0ULL;  // keys unique (idx in low bits)
  }

  // ---- Majority vote over the 16 winners' labels ----
  int myLabel = 0;
  if (lane < 16) myLabel = labels[(uint32_t)myWin];  // low 32 bits = column idx

  int c = 0;
  #pragma unroll
  for (int s = 0; s < 16; ++s) {
    int ls = __shfl(myLabel, s);
    c += (ls == myLabel) ? 1 : 0;
  }
  // maximize count, then minimize label (argmax-first semantics)
  int vkey = (lane < 16) ? ((c << 7) | (127 - myLabel)) : 0;
  #pragma unroll
  for (int off = 32; off >= 1; off >>= 1) {
    int o = __shfl_xor(vkey, off);
    vkey = (o > vkey) ? o : vkey;
  }
  if (lane == 0) out[row] = 127 - (vkey & 127);
}

extern "C" void kernel_launch(void* const* d_in, const int* in_sizes, int n_in,
                              void* d_out, int out_size, void* d_ws, size_t ws_size,
                              hipStream_t stream) {
  const float* dist   = (const float*)d_in[0];
  const int*   labels = (const int*)d_in[1];
  int*         out    = (int*)d_out;
  const int rows = out_size;          // 8192
  // 4 rows per 256-thread block (one wave per row); grid divides exactly.
  KNNC_20272245637217_kernel<<<rows / 4, 256, 0, stream>>>(dist, labels, out);
}

// Round 2
// 655.842 us; speedup vs baseline: 1.0658x; 1.0658x over previous
//
#include <hip/hip_runtime.h>
#include <stdint.h>

#define COLS 16384
#define POOLCAP 256
typedef unsigned long long u64;
typedef float vf4 __attribute__((ext_vector_type(4)));

// Order-preserving float32 -> uint32 mapping (ascending float == ascending uint).
__device__ __forceinline__ uint32_t f2key(float x) {
  uint32_t u = __float_as_uint(x);
  u ^= (uint32_t)((int32_t)u >> 31) | 0x80000000u;
  return u;
}

__global__ __launch_bounds__(256, 4) void KNNC_20272245637217_kernel(
    const float* __restrict__ dist,
    const int* __restrict__ labels,
    int* __restrict__ out) {
  const int wave = threadIdx.x >> 6;   // 4 waves/block, one row each
  const int lane = threadIdx.x & 63;
  const int row  = blockIdx.x * 4 + wave;

  __shared__ u64 poolK[4][POOLCAP];    // (sortable value bits << 32) | column idx
  __shared__ int cnt[4];
  if (threadIdx.x < 4) cnt[threadIdx.x] = 0;
  __syncthreads();

  const vf4* __restrict__ rp = (const vf4*)(dist + (size_t)row * COLS);

  // Two 8-wide register buffers; every dist byte is loaded exactly once (NT).
  vf4 A8[8], B8[8];
#define LOAD8(b, buf) { _Pragma("unroll") \
  for (int u = 0; u < 8; ++u) (buf)[u] = __builtin_nontemporal_load(rp + (b)*512 + u*64 + lane); }

  LOAD8(0, A8)
  LOAD8(1, B8)

  // ---- Stage A: lane-min over first 4096 elements (batches 0,1 stay in regs) ----
  float m = __builtin_inff();
  #pragma unroll
  for (int u = 0; u < 8; ++u)
    m = fminf(m, fminf(fminf(A8[u].x, A8[u].y), fminf(A8[u].z, A8[u].w)));
  #pragma unroll
  for (int u = 0; u < 8; ++u)
    m = fminf(m, fminf(fminf(B8[u].x, B8[u].y), fminf(B8[u].z, B8[u].w)));

  // ---- T = exact 16th smallest of the 64 lane minima (bitonic sort, 21 stages) ----
  // T >= row's true 16th smallest: the 16 smallest lane-minima are 16 distinct
  // row elements <= T. Expected pool size ~74, P(>256) ~ 1e-11 per row.
  float v = m;
  #pragma unroll
  for (int k = 2; k <= 64; k <<= 1) {
    #pragma unroll
    for (int j = k >> 1; j >= 1; j >>= 1) {
      float o = __shfl_xor(v, j);
      bool keepMin = (((lane & j) == 0) == ((lane & k) == 0));
      v = keepMin ? fminf(v, o) : fmaxf(v, o);
    }
  }
  const float T = __shfl(v, 15);

#define PUSH(x, c) { if ((x) <= T) { \
    int _s = atomicAdd(&cnt[wave], 1); \
    if (_s < POOLCAP) poolK[wave][_s] = (((u64)f2key(x)) << 32) | (u64)(uint32_t)(c); } }
#define PROC8(buf, b) { _Pragma("unroll") \
  for (int u = 0; u < 8; ++u) { \
    vf4 w = (buf)[u]; \
    float mn = fminf(fminf(w.x, w.y), fminf(w.z, w.w)); \
    if (mn <= T) { \
      int col = ((b)*8 + u) * 256 + lane * 4; \
      PUSH(w.x, col) PUSH(w.y, col+1) PUSH(w.z, col+2) PUSH(w.w, col+3) \
    } } }

  // ---- Stage B: double-buffered process/prefetch; batches 0,1 already resident ----
  PROC8(A8, 0)
  LOAD8(2, A8)
  PROC8(B8, 1)
  LOAD8(3, B8)
  PROC8(A8, 2)
  LOAD8(4, A8)
  PROC8(B8, 3)
  LOAD8(5, B8)
  PROC8(A8, 4)
  LOAD8(6, A8)
  PROC8(B8, 5)
  LOAD8(7, B8)
  PROC8(A8, 6)
  PROC8(B8, 7)

  __syncthreads();

  // ---- Exact top-16 extraction (u64 keys reproduce top_k's index tie-break) ----
  int C = cnt[wave];
  if (C > POOLCAP) C = POOLCAP;   // defensive; C >= 16 guaranteed by T's construction

  u64 key[4];
  #pragma unroll
  for (int t = 0; t < 4; ++t) {
    int p = lane + 64 * t;
    key[t] = (p < C) ? poolK[wave][p] : ~0ULL;
  }

  u64 myWin = ~0ULL;
  for (int r = 0; r < 16; ++r) {
    u64 k = key[0];
    k = (key[1] < k) ? key[1] : k;
    k = (key[2] < k) ? key[2] : k;
    k = (key[3] < k) ? key[3] : k;
    #pragma unroll
    for (int off = 32; off >= 1; off >>= 1) {
      u64 o = __shfl_xor(k, off);
      k = (o < k) ? o : k;
    }
    if (lane == r) myWin = k;           // lane r records the r-th smallest
    #pragma unroll
    for (int t = 0; t < 4; ++t)
      if (key[t] == k) key[t] = ~0ULL;  // keys unique (idx in low bits)
  }

  // ---- Majority vote over the 16 winners' labels ----
  int myLabel = 0;
  if (lane < 16) myLabel = labels[(uint32_t)myWin];  // low 32 bits = column idx

  int c = 0;
  #pragma unroll
  for (int s = 0; s < 16; ++s) {
    int ls = __shfl(myLabel, s);
    c += (ls == myLabel) ? 1 : 0;
  }
  // maximize count, then minimize label (argmax-first semantics)
  int vkey = (lane < 16) ? ((c << 7) | (127 - myLabel)) : 0;
  #pragma unroll
  for (int off = 32; off >= 1; off >>= 1) {
    int o = __shfl_xor(vkey, off);
    vkey = (o > vkey) ? o : vkey;
  }
  if (lane == 0) out[row] = 127 - (vkey & 127);
}

extern "C" void kernel_launch(void* const* d_in, const int* in_sizes, int n_in,
                              void* d_out, int out_size, void* d_ws, size_t ws_size,
                              hipStream_t stream) {
  const float* dist   = (const float*)d_in[0];
  const int*   labels = (const int*)d_in[1];
  int*         out    = (int*)d_out;
  const int rows = out_size;          // 8192
  KNNC_20272245637217_kernel<<<rows / 4, 256, 0, stream>>>(dist, labels, out);
}